// Round 1
// baseline (24678.011 us; speedup 1.0000x reference)
//
#include <hip/hip_runtime.h>
#include <cstddef>

// ---------------------------------------------------------------------------
// Agent LSTM PPO forward, MI355X.
//
// Key structural facts:
//  * Only h_{S-1} feeds the output (z[:, -1, :]) -> the per-timestep dense
//    stack in the reference is dead code except at t = S-1.
//  * LSTM recurrence fused with the input projection: gates = comb @ W,
//    comb = [x_t (128) | h_{t-1} (256)], W = [Wf|Wi|Wc|Wo] column slices.
//  * Grid = 16 batch-tiles x 16 hid-tiles = 256 wgs (1 per CU, LDS-capped).
//    Each wg: 16 batch rows x 16 hid units (=64 gate cols), weight slice
//    (384x64 fp32 = 96KB) resident in LDS, c-state in registers.
//    Per step: exchange h slices via global double buffer + per-group
//    16-wg counter barrier (release add / acquire spin, one counter per
//    (group, step) so no reset races).
// ---------------------------------------------------------------------------

#define S_LEN 512
#define OBS_D 128
#define HIDN  256
#define COMBD 384          // OBS_D + HIDN
#define BATCH 256
#define MBT   16           // batch tiles
#define NNT   16           // hid tiles  (= sync group size)
#define BT    16           // batch rows per wg
#define HT    16           // hid units per wg
#define NCOL  64           // 4 gates * HT
#define ACT_DIM 32

#define W_LDS_BYTES   (COMBD * NCOL * 4)          // 98304
#define COMB_LDS_OFF  W_LDS_BYTES
#define COMB_LDS_BYTES (BT * COMBD * 4)           // 24576
#define GATE_LDS_OFF  (COMB_LDS_OFF + COMB_LDS_BYTES)
#define GATE_LDS_BYTES (BT * NCOL * 4)            // 4096
#define LDS_BYTES     (GATE_LDS_OFF + GATE_LDS_BYTES)  // 126976 (<160K, 1 wg/CU)

// ws layout: hbuf[2][256][256] f32 (512KB) | counters[16][512] u32 (32KB)
#define HBUF_ELEMS (2 * BATCH * HIDN)
#define CNT_OFF_BYTES (HBUF_ELEMS * 4)

__device__ __forceinline__ float sigf(float x) { return 1.0f / (1.0f + __expf(-x)); }
__device__ __forceinline__ float tanh_f(float x) { return 2.0f / (1.0f + __expf(-2.0f * x)) - 1.0f; }

extern __shared__ char smem_raw[];

__global__ void __launch_bounds__(256, 1)
lstm_recurrence(const float* __restrict__ obs,
                const float* __restrict__ Wfp, const float* __restrict__ bfp,
                const float* __restrict__ Wip, const float* __restrict__ bip,
                const float* __restrict__ Wcp, const float* __restrict__ bcp,
                const float* __restrict__ Wop, const float* __restrict__ bop,
                float* __restrict__ hbuf,          // [2][BATCH][HIDN]
                unsigned int* __restrict__ cnt)    // [MBT][S_LEN]
{
    float* Wlds  = (float*)smem_raw;                        // [COMBD][NCOL]
    float* combL = (float*)(smem_raw + COMB_LDS_OFF);       // [BT][COMBD]
    float* gateL = (float*)(smem_raw + GATE_LDS_OFF);       // [BT][NCOL]

    const int tid  = threadIdx.x;
    const int gbi  = blockIdx.x & (MBT - 1);     // batch tile
    const int gnj  = blockIdx.x >> 4;            // hid tile
    const int bbase = gbi * BT;
    const int j0    = gnj * HT;

    // ---- stage weight slice: cols [j0, j0+HT) of each gate matrix --------
    {
        const float* Wg[4] = { Wfp, Wip, Wcp, Wop };
        for (int g = 0; g < 4; ++g) {
            const float* src = Wg[g];
            for (int idx = tid; idx < COMBD * HT; idx += 256) {
                const int k = idx >> 4, cc = idx & 15;
                Wlds[k * NCOL + g * HT + cc] = src[k * HIDN + j0 + cc];
            }
        }
    }

    // gate-phase thread mapping: (bb, jj) pair; c-state lives here.
    const int bb = tid >> 4, jj = tid & 15;
    const float Bf = bfp[j0 + jj], Bi = bip[j0 + jj];
    const float Bc = bcp[j0 + jj], Bo = bop[j0 + jj];
    float creg = 0.0f;

    // GEMM thread mapping: col c, rows {w, w+4, w+8, w+12}
    const int c = tid & 63, w = tid >> 6;

    unsigned int* mycnt = cnt + gbi * S_LEN;
    __syncthreads();

#pragma unroll 1
    for (int t = 0; t < S_LEN; ++t) {
        // ---- stage comb = [x_t | h_{t-1}] into LDS -----------------------
        {
            const int r = tid >> 4, q = tid & 15;
            const float* orow = obs + ((size_t)(bbase + r) * S_LEN + t) * OBS_D;
            *(float4*)(combL + r * COMBD + q * 4)      = *(const float4*)(orow + q * 4);
            *(float4*)(combL + r * COMBD + 64 + q * 4) = *(const float4*)(orow + 64 + q * 4);
            const float* hrow = hbuf + (size_t)(t & 1) * (BATCH * HIDN)
                                     + (size_t)(bbase + r) * HIDN;
            *(float4*)(combL + r * COMBD + OBS_D +   0 + q * 4) = *(const float4*)(hrow +   0 + q * 4);
            *(float4*)(combL + r * COMBD + OBS_D +  64 + q * 4) = *(const float4*)(hrow +  64 + q * 4);
            *(float4*)(combL + r * COMBD + OBS_D + 128 + q * 4) = *(const float4*)(hrow + 128 + q * 4);
            *(float4*)(combL + r * COMBD + OBS_D + 192 + q * 4) = *(const float4*)(hrow + 192 + q * 4);
        }
        __syncthreads();

        // ---- GEMM: gates[16][64] += comb[16][384] @ Wlds[384][64] --------
        float acc0 = 0.f, acc1 = 0.f, acc2 = 0.f, acc3 = 0.f;
#pragma unroll 4
        for (int k = 0; k < COMBD; k += 4) {
            const float4 x0 = *(const float4*)(combL + (w     ) * COMBD + k);
            const float4 x1 = *(const float4*)(combL + (w +  4) * COMBD + k);
            const float4 x2 = *(const float4*)(combL + (w +  8) * COMBD + k);
            const float4 x3 = *(const float4*)(combL + (w + 12) * COMBD + k);
            const float w0 = Wlds[(k + 0) * NCOL + c];
            const float w1 = Wlds[(k + 1) * NCOL + c];
            const float w2 = Wlds[(k + 2) * NCOL + c];
            const float w3 = Wlds[(k + 3) * NCOL + c];
            acc0 = fmaf(x0.x, w0, acc0); acc0 = fmaf(x0.y, w1, acc0);
            acc0 = fmaf(x0.z, w2, acc0); acc0 = fmaf(x0.w, w3, acc0);
            acc1 = fmaf(x1.x, w0, acc1); acc1 = fmaf(x1.y, w1, acc1);
            acc1 = fmaf(x1.z, w2, acc1); acc1 = fmaf(x1.w, w3, acc1);
            acc2 = fmaf(x2.x, w0, acc2); acc2 = fmaf(x2.y, w1, acc2);
            acc2 = fmaf(x2.z, w2, acc2); acc2 = fmaf(x2.w, w3, acc2);
            acc3 = fmaf(x3.x, w0, acc3); acc3 = fmaf(x3.y, w1, acc3);
            acc3 = fmaf(x3.z, w2, acc3); acc3 = fmaf(x3.w, w3, acc3);
        }
        gateL[(w     ) * NCOL + c] = acc0;
        gateL[(w +  4) * NCOL + c] = acc1;
        gateL[(w +  8) * NCOL + c] = acc2;
        gateL[(w + 12) * NCOL + c] = acc3;
        __syncthreads();

        // ---- gate nonlinearities + state update (thread owns (bb,jj)) ----
        {
            const float fg = sigf  (gateL[bb * NCOL +      jj] + Bf);
            const float ig = sigf  (gateL[bb * NCOL + 16 + jj] + Bi);
            const float cg = tanh_f(gateL[bb * NCOL + 32 + jj] + Bc);
            const float og = sigf  (gateL[bb * NCOL + 48 + jj] + Bo);
            creg = fg * creg + ig * cg;
            const float hnew = og * tanh_f(creg);
            hbuf[(size_t)((t + 1) & 1) * (BATCH * HIDN)
                 + (size_t)(bbase + bb) * HIDN + j0 + jj] = hnew;
        }

        // ---- group barrier: 16 wgs sharing this batch tile ---------------
        __threadfence();          // release: h writes -> device scope
        __syncthreads();
        if (tid == 0) {
            unsigned int* slot = mycnt + t;
            __hip_atomic_fetch_add(slot, 1u, __ATOMIC_RELEASE, __HIP_MEMORY_SCOPE_AGENT);
            while (__hip_atomic_load(slot, __ATOMIC_ACQUIRE, __HIP_MEMORY_SCOPE_AGENT) < NNT) {
                __builtin_amdgcn_s_sleep(1);
            }
        }
        __syncthreads();
        __threadfence();          // acquire: invalidate L1 before reading peers' h
    }
}

// ---------------------------------------------------------------------------
// Head kernel: z1 = relu(h@W1+b1), z2 = relu(z1@W2+b2), actor/critic heads,
// log_softmax + gather + entropy. 64 wgs x 4 batch rows. ~0.24 GFLOP total.
// ---------------------------------------------------------------------------
__global__ void __launch_bounds__(256)
head_kernel(const float* __restrict__ hfin,      // hbuf[0]: [BATCH][HIDN]
            const float* __restrict__ W1, const float* __restrict__ b1v,
            const float* __restrict__ W2, const float* __restrict__ b2v,
            const float* __restrict__ A1, const float* __restrict__ a1v,
            const float* __restrict__ A2, const float* __restrict__ a2v,
            const float* __restrict__ A3, const float* __restrict__ a3v,
            const float* __restrict__ C1, const float* __restrict__ c1v,
            const float* __restrict__ C2, const float* __restrict__ c2v,
            const float* __restrict__ C3, const float* __restrict__ c3v,
            const int* __restrict__ action,
            float* __restrict__ out)             // [3][BATCH]
{
    __shared__ float e0[4][HIDN];
    __shared__ float z1s[4][512];
    __shared__ float z2s[4][512];
    __shared__ float aL[4][64], vL[4][64], a2L[4][64], v2L[4][64];
    __shared__ float lgL[4][ACT_DIM];
    __shared__ float valL[4];

    const int tid = threadIdx.x;
    const int b0 = blockIdx.x * 4;

    for (int idx = tid; idx < 4 * HIDN; idx += 256) {
        const int r = idx >> 8, k = idx & 255;
        e0[r][k] = hfin[(size_t)(b0 + r) * HIDN + k];
    }
    __syncthreads();

    // z1 = relu(e0 @ W1 + b1)  (K=256 -> N=512)
    for (int i = 0; i < 8; ++i) {
        const int idx = i * 256 + tid;
        const int r = idx >> 9, cc = idx & 511;
        float acc = b1v[cc];
        for (int k = 0; k < HIDN; ++k) acc = fmaf(e0[r][k], W1[k * 512 + cc], acc);
        z1s[r][cc] = fmaxf(acc, 0.0f);
    }
    __syncthreads();

    // z2 = relu(z1 @ W2 + b2)  (K=512 -> N=512)
    for (int i = 0; i < 8; ++i) {
        const int idx = i * 256 + tid;
        const int r = idx >> 9, cc = idx & 511;
        float acc = b2v[cc];
        for (int k = 0; k < 512; ++k) acc = fmaf(z1s[r][k], W2[k * 512 + cc], acc);
        z2s[r][cc] = fmaxf(acc, 0.0f);
    }
    __syncthreads();

    // first head layers (K=512 -> 64), actor + critic
    {
        const int r = tid >> 6, j = tid & 63;
        float acc = a1v[j], accv = c1v[j];
        for (int k = 0; k < 512; ++k) {
            const float e = z2s[r][k];
            acc  = fmaf(e, A1[k * 64 + j], acc);
            accv = fmaf(e, C1[k * 64 + j], accv);
        }
        aL[r][j] = tanh_f(acc);
        vL[r][j] = tanh_f(accv);
    }
    __syncthreads();
    {
        const int r = tid >> 6, j = tid & 63;
        float acc = a2v[j], accv = c2v[j];
        for (int k = 0; k < 64; ++k) {
            acc  = fmaf(aL[r][k], A2[k * 64 + j], acc);
            accv = fmaf(vL[r][k], C2[k * 64 + j], accv);
        }
        a2L[r][j] = tanh_f(acc);
        v2L[r][j] = tanh_f(accv);
    }
    __syncthreads();
    if (tid < 128) {
        const int r = tid >> 5, j = tid & 31;
        float acc = a3v[j];
        for (int k = 0; k < 64; ++k) acc = fmaf(a2L[r][k], A3[k * ACT_DIM + j], acc);
        lgL[r][j] = acc;
    }
    if (tid >= 128 && tid < 132) {
        const int r = tid - 128;
        float acc = c3v[0];
        for (int k = 0; k < 64; ++k) acc = fmaf(v2L[r][k], C3[k], acc);
        valL[r] = acc;
    }
    __syncthreads();

    // softmax / logp / entropy: wave w handles row w (lanes 0..31 hold logits)
    {
        const int wv = tid >> 6, lane = tid & 63;
        const float x = (lane < ACT_DIM) ? lgL[wv][lane] : -3.4e38f;
        float m = x;
        for (int off = 32; off; off >>= 1) m = fmaxf(m, __shfl_xor(m, off));
        const float p = (lane < ACT_DIM) ? __expf(x - m) : 0.0f;
        float s = p;
        for (int off = 32; off; off >>= 1) s += __shfl_xor(s, off);
        const float logs = logf(s);
        const float lp = x - m - logs;
        const int act = action[b0 + wv];
        float sel = (lane == act) ? lp : 0.0f;
        for (int off = 32; off; off >>= 1) sel += __shfl_xor(sel, off);
        float et = (lane < ACT_DIM) ? p * lp : 0.0f;
        for (int off = 32; off; off >>= 1) et += __shfl_xor(et, off);
        if (lane == 0) {
            const int b = b0 + wv;
            out[b]            = sel;          // logp
            out[BATCH + b]    = -et / s;      // entropy
            out[2 * BATCH + b] = valL[wv];    // value
        }
    }
}

extern "C" void kernel_launch(void* const* d_in, const int* in_sizes, int n_in,
                              void* d_out, int out_size, void* d_ws, size_t ws_size,
                              hipStream_t stream) {
    const float* obs = (const float*)d_in[0];
    const int*   action = (const int*)d_in[1];
    const float* Wfp = (const float*)d_in[2];  const float* bfp = (const float*)d_in[3];
    const float* Wip = (const float*)d_in[4];  const float* bip = (const float*)d_in[5];
    const float* Wcp = (const float*)d_in[6];  const float* bcp = (const float*)d_in[7];
    const float* Wop = (const float*)d_in[8];  const float* bop = (const float*)d_in[9];
    const float* W1  = (const float*)d_in[10]; const float* b1v = (const float*)d_in[11];
    const float* W2  = (const float*)d_in[12]; const float* b2v = (const float*)d_in[13];
    const float* A1  = (const float*)d_in[14]; const float* a1v = (const float*)d_in[15];
    const float* A2  = (const float*)d_in[16]; const float* a2v = (const float*)d_in[17];
    const float* A3  = (const float*)d_in[18]; const float* a3v = (const float*)d_in[19];
    const float* C1  = (const float*)d_in[20]; const float* c1v = (const float*)d_in[21];
    const float* C2  = (const float*)d_in[22]; const float* c2v = (const float*)d_in[23];
    const float* C3  = (const float*)d_in[24]; const float* c3v = (const float*)d_in[25];

    float* hbuf = (float*)d_ws;
    unsigned int* cnt = (unsigned int*)((char*)d_ws + CNT_OFF_BYTES);

    // zero h_0 (first read buffer) and the barrier counters; ws is 0xAA-poisoned.
    hipMemsetAsync(d_ws, 0, BATCH * HIDN * sizeof(float), stream);
    hipMemsetAsync((char*)d_ws + CNT_OFF_BYTES, 0, MBT * S_LEN * sizeof(unsigned int), stream);

    hipFuncSetAttribute((const void*)lstm_recurrence,
                        hipFuncAttributeMaxDynamicSharedMemorySize, LDS_BYTES);

    lstm_recurrence<<<dim3(256), dim3(256), LDS_BYTES, stream>>>(
        obs, Wfp, bfp, Wip, bip, Wcp, bcp, Wop, bop, hbuf, cnt);

    // after step 511, h_final sits in hbuf[0]
    head_kernel<<<dim3(64), dim3(256), 0, stream>>>(
        hbuf, W1, b1v, W2, b2v, A1, a1v, A2, a2v, A3, a3v,
        C1, c1v, C2, c2v, C3, c3v, action, (float*)d_out);
}

// Round 2
// 1361.061 us; speedup vs baseline: 18.1314x; 18.1314x over previous
//
#include <hip/hip_runtime.h>
#include <cstddef>

// ---------------------------------------------------------------------------
// Agent LSTM PPO forward, MI355X — round 2.
//
//  * Only h_{S-1} feeds the head -> per-timestep dense stack is dead code.
//  * 16 batch-tiles x 16 hid-tiles = 256 wgs (1/CU, co-resident).
//  * Gate GEMM: bf16 MFMA 16x16x32, weights RESIDENT IN REGISTERS
//    (12 B-frags/wave = 48 VGPR; wave w owns gate w). Zero LDS weight
//    traffic in the loop. A/B packed with the SAME k-mapping -> result is
//    invariant to the hardware's k-permutation; only C/D layout assumed
//    (m89-verified: col=lane&15, row=(lane>>4)*4+reg).
//  * Cross-wg h exchange: RELAXED agent-scope atomics (sc0 sc1 -> L3),
//    NO fences (no buffer_inv/wbl2 L2 thrash). Release = s_waitcnt vmcnt(0)
//    before counter add; acquire = in-order issue after spin + barrier.
//    Per-(group,step) counters -> no reset races; 2-deep h double buffer.
// ---------------------------------------------------------------------------

#define S_LEN 512
#define OBS_D 128
#define HIDN  256
#define BATCH 256
#define MBT   16           // batch tiles
#define NNT   16           // hid tiles (= sync group size)
#define BT    16           // batch rows per wg
#define HT    16           // hid units per wg
#define ACT_DIM 32

#define COMB_STRIDE 392    // bf16 elems per row (384 + 8 pad): stride 784B
                           // -> word-bank = 4*((r+q)&7): conflict-free b128

typedef __bf16 bf16x8 __attribute__((ext_vector_type(8)));
typedef float  f32x4  __attribute__((ext_vector_type(4)));
typedef unsigned long long u64x2 __attribute__((ext_vector_type(2)));

// ws layout: hbuf bf16 [2][BATCH][HIDN] (256KB) | cnt u32 [MBT][S_LEN] (32KB)
#define CNT_OFF_BYTES (2 * BATCH * HIDN * 2)

__device__ __forceinline__ float sigf(float x)   { return 1.0f / (1.0f + __expf(-x)); }
__device__ __forceinline__ float tanh_f(float x) { return 2.0f / (1.0f + __expf(-2.0f * x)) - 1.0f; }

__global__ void __launch_bounds__(256, 1)
lstm_recurrence(const float* __restrict__ obs,
                const float* __restrict__ Wfp, const float* __restrict__ bfp,
                const float* __restrict__ Wip, const float* __restrict__ bip,
                const float* __restrict__ Wcp, const float* __restrict__ bcp,
                const float* __restrict__ Wop, const float* __restrict__ bop,
                unsigned short* __restrict__ hbuf,   // bf16 bits [2][BATCH][HIDN]
                unsigned int* __restrict__ cnt)      // [MBT][S_LEN]
{
    __shared__ __align__(16) unsigned short combL[BT][COMB_STRIDE]; // bf16 comb
    __shared__ float gateL[BT][66];                                 // padded (+2)
    __shared__ unsigned short htmp[BT][HT];

    const int tid  = threadIdx.x;
    const int gbi  = blockIdx.x & (MBT - 1);
    const int gnj  = blockIdx.x >> 4;
    const int bbase = gbi * BT;
    const int j0    = gnj * HT;

    const int wv  = tid >> 6;          // wave = gate index (0:f 1:i 2:c 3:o)
    const int lane = tid & 63;
    const int l15 = lane & 15, lg = lane >> 4;

    // ---- one-time: weight slice -> register B-fragments ------------------
    const float* Wsrc = (wv == 0) ? Wfp : (wv == 1) ? Wip : (wv == 2) ? Wcp : Wop;
    const float* Bsrc = (wv == 0) ? bfp : (wv == 1) ? bip : (wv == 2) ? bcp : bop;
    const int wcol = j0 + l15;
    bf16x8 bfrag[12];
#pragma unroll
    for (int kk = 0; kk < 12; ++kk) {
        bf16x8 b;
#pragma unroll
        for (int e = 0; e < 8; ++e)
            b[e] = (__bf16)Wsrc[(size_t)(kk * 32 + lg * 8 + e) * HIDN + wcol];
        bfrag[kk] = b;
    }
    const float biasw = Bsrc[wcol];    // D col = wv*16 + l15 -> gate bias

    // staging mapping: thread (sr, sq) owns row sr, 16-col chunk sq
    const int sr = tid >> 4, sq = tid & 15;
    const float* obase = obs + (size_t)(bbase + sr) * S_LEN * OBS_D;

    // nonlin mapping: thread owns (bb, jj); fp32 c-state in register
    const int bb = tid >> 4, jj = tid & 15;
    float creg = 0.0f;

    unsigned int* gcnt = cnt + gbi * S_LEN;
    unsigned long long* hb64 = (unsigned long long*)hbuf;
    char* combB = (char*)&combL[0][0];

#pragma unroll 1
    for (int t = 0; t < S_LEN; ++t) {
        // (A) issue x_t loads early — they overlap the spin below
        const float* orow = obase + (size_t)t * OBS_D;
        const float4 xa = *(const float4*)(orow + sq * 8);
        const float4 xb = *(const float4*)(orow + sq * 8 + 4);

        // (B) wait until all 16 wgs of this batch group published h_{t-1}
        if (t > 0) {
            if (tid == 0) {
                unsigned int* slot = gcnt + (t - 1);
                while (__hip_atomic_load(slot, __ATOMIC_RELAXED,
                                         __HIP_MEMORY_SCOPE_AGENT) < NNT)
                    __builtin_amdgcn_s_sleep(2);
            }
            __syncthreads();
        }

        // (C) stage comb = [x_t | h_{t-1}] (bf16) into LDS
        {
            bf16x8 xv;
            xv[0] = (__bf16)xa.x; xv[1] = (__bf16)xa.y;
            xv[2] = (__bf16)xa.z; xv[3] = (__bf16)xa.w;
            xv[4] = (__bf16)xb.x; xv[5] = (__bf16)xb.y;
            xv[6] = (__bf16)xb.z; xv[7] = (__bf16)xb.w;
            *(bf16x8*)(combB + sr * (COMB_STRIDE * 2) + sq * 16) = xv;

            char* hdst = combB + sr * (COMB_STRIDE * 2) + 256 + sq * 32;
            if (t > 0) {
                unsigned long long* src = hb64 +
                    ((size_t)(t & 1) * BATCH * HIDN +
                     (size_t)(bbase + sr) * HIDN + sq * 16) / 4;
                u64x2 p0, p1;
                p0[0] = __hip_atomic_load(src + 0, __ATOMIC_RELAXED, __HIP_MEMORY_SCOPE_AGENT);
                p0[1] = __hip_atomic_load(src + 1, __ATOMIC_RELAXED, __HIP_MEMORY_SCOPE_AGENT);
                p1[0] = __hip_atomic_load(src + 2, __ATOMIC_RELAXED, __HIP_MEMORY_SCOPE_AGENT);
                p1[1] = __hip_atomic_load(src + 3, __ATOMIC_RELAXED, __HIP_MEMORY_SCOPE_AGENT);
                *(u64x2*)(hdst)      = p0;
                *(u64x2*)(hdst + 16) = p1;
            } else {
                u64x2 z; z[0] = 0ull; z[1] = 0ull;
                *(u64x2*)(hdst)      = z;
                *(u64x2*)(hdst + 16) = z;
            }
        }
        __syncthreads();

        // (D) gate GEMM: 12 MFMAs, B-frags from registers
        {
            f32x4 acc; acc[0] = biasw; acc[1] = biasw; acc[2] = biasw; acc[3] = biasw;
            const char* abase = combB + l15 * (COMB_STRIDE * 2) + lg * 16;
#pragma unroll
            for (int kk = 0; kk < 12; ++kk) {
                const bf16x8 a = *(const bf16x8*)(abase + kk * 64);
                acc = __builtin_amdgcn_mfma_f32_16x16x32_bf16(a, bfrag[kk], acc, 0, 0, 0);
            }
#pragma unroll
            for (int q = 0; q < 4; ++q)
                gateL[lg * 4 + q][wv * 16 + l15] = acc[q];
        }
        __syncthreads();

        // (E) nonlinearities + state update
        {
            const float fg = sigf  (gateL[bb][     jj]);
            const float ig = sigf  (gateL[bb][16 + jj]);
            const float cg = tanh_f(gateL[bb][32 + jj]);
            const float og = sigf  (gateL[bb][48 + jj]);
            creg = fg * creg + ig * cg;
            const float hnew = og * tanh_f(creg);
            const __bf16 hb = (__bf16)hnew;
            htmp[bb][jj] = __builtin_bit_cast(unsigned short, hb);
        }
        __syncthreads();

        // (F) publish h slice (wave 0) + signal counter (fence-free release)
        if (tid < 64) {
            const int hr = tid >> 2, hc = (tid & 3) * 4;
            const unsigned short* hp = &htmp[hr][hc];
            unsigned long long v =  ((unsigned long long)hp[0])
                                 | (((unsigned long long)hp[1]) << 16)
                                 | (((unsigned long long)hp[2]) << 32)
                                 | (((unsigned long long)hp[3]) << 48);
            unsigned long long* dst = hb64 +
                ((size_t)((t + 1) & 1) * BATCH * HIDN +
                 (size_t)(bbase + hr) * HIDN + j0 + hc) / 4;
            __hip_atomic_store(dst, v, __ATOMIC_RELAXED, __HIP_MEMORY_SCOPE_AGENT);
        }
        if (tid == 0) {
            asm volatile("s_waitcnt vmcnt(0)" ::: "memory");  // h visible @ L3
            __hip_atomic_fetch_add(gcnt + t, 1u, __ATOMIC_RELAXED,
                                   __HIP_MEMORY_SCOPE_AGENT);
        }
    }
}

// ---------------------------------------------------------------------------
// Head kernel (unchanged math; h input is now bf16). 64 wgs x 4 batch rows.
// ---------------------------------------------------------------------------
__global__ void __launch_bounds__(256)
head_kernel(const unsigned short* __restrict__ hfin,   // bf16 bits [BATCH][HIDN]
            const float* __restrict__ W1, const float* __restrict__ b1v,
            const float* __restrict__ W2, const float* __restrict__ b2v,
            const float* __restrict__ A1, const float* __restrict__ a1v,
            const float* __restrict__ A2, const float* __restrict__ a2v,
            const float* __restrict__ A3, const float* __restrict__ a3v,
            const float* __restrict__ C1, const float* __restrict__ c1v,
            const float* __restrict__ C2, const float* __restrict__ c2v,
            const float* __restrict__ C3, const float* __restrict__ c3v,
            const int* __restrict__ action,
            float* __restrict__ out)                   // [3][BATCH]
{
    __shared__ float e0[4][HIDN];
    __shared__ float z1s[4][512];
    __shared__ float z2s[4][512];
    __shared__ float aL[4][64], vL[4][64], a2L[4][64], v2L[4][64];
    __shared__ float lgL[4][ACT_DIM];
    __shared__ float valL[4];

    const int tid = threadIdx.x;
    const int b0 = blockIdx.x * 4;

    for (int idx = tid; idx < 4 * HIDN; idx += 256) {
        const int r = idx >> 8, k = idx & 255;
        const unsigned int u = ((unsigned int)hfin[(size_t)(b0 + r) * HIDN + k]) << 16;
        e0[r][k] = __builtin_bit_cast(float, u);
    }
    __syncthreads();

    for (int i = 0; i < 8; ++i) {
        const int idx = i * 256 + tid;
        const int r = idx >> 9, cc = idx & 511;
        float acc = b1v[cc];
        for (int k = 0; k < HIDN; ++k) acc = fmaf(e0[r][k], W1[k * 512 + cc], acc);
        z1s[r][cc] = fmaxf(acc, 0.0f);
    }
    __syncthreads();

    for (int i = 0; i < 8; ++i) {
        const int idx = i * 256 + tid;
        const int r = idx >> 9, cc = idx & 511;
        float acc = b2v[cc];
        for (int k = 0; k < 512; ++k) acc = fmaf(z1s[r][k], W2[k * 512 + cc], acc);
        z2s[r][cc] = fmaxf(acc, 0.0f);
    }
    __syncthreads();

    {
        const int r = tid >> 6, j = tid & 63;
        float acc = a1v[j], accv = c1v[j];
        for (int k = 0; k < 512; ++k) {
            const float e = z2s[r][k];
            acc  = fmaf(e, A1[k * 64 + j], acc);
            accv = fmaf(e, C1[k * 64 + j], accv);
        }
        aL[r][j] = tanh_f(acc);
        vL[r][j] = tanh_f(accv);
    }
    __syncthreads();
    {
        const int r = tid >> 6, j = tid & 63;
        float acc = a2v[j], accv = c2v[j];
        for (int k = 0; k < 64; ++k) {
            acc  = fmaf(aL[r][k], A2[k * 64 + j], acc);
            accv = fmaf(vL[r][k], C2[k * 64 + j], accv);
        }
        a2L[r][j] = tanh_f(acc);
        v2L[r][j] = tanh_f(accv);
    }
    __syncthreads();
    if (tid < 128) {
        const int r = tid >> 5, j = tid & 31;
        float acc = a3v[j];
        for (int k = 0; k < 64; ++k) acc = fmaf(a2L[r][k], A3[k * ACT_DIM + j], acc);
        lgL[r][j] = acc;
    }
    if (tid >= 128 && tid < 132) {
        const int r = tid - 128;
        float acc = c3v[0];
        for (int k = 0; k < 64; ++k) acc = fmaf(v2L[r][k], C3[k], acc);
        valL[r] = acc;
    }
    __syncthreads();

    {
        const int wv = tid >> 6, lane = tid & 63;
        const float x = (lane < ACT_DIM) ? lgL[wv][lane] : -3.4e38f;
        float m = x;
        for (int off = 32; off; off >>= 1) m = fmaxf(m, __shfl_xor(m, off));
        const float p = (lane < ACT_DIM) ? __expf(x - m) : 0.0f;
        float s = p;
        for (int off = 32; off; off >>= 1) s += __shfl_xor(s, off);
        const float logs = logf(s);
        const float lp = x - m - logs;
        const int act = action[b0 + wv];
        float sel = (lane == act) ? lp : 0.0f;
        for (int off = 32; off; off >>= 1) sel += __shfl_xor(sel, off);
        float et = (lane < ACT_DIM) ? p * lp : 0.0f;
        for (int off = 32; off; off >>= 1) et += __shfl_xor(et, off);
        if (lane == 0) {
            const int b = b0 + wv;
            out[b]             = sel;
            out[BATCH + b]     = -et / s;
            out[2 * BATCH + b] = valL[wv];
        }
    }
}

extern "C" void kernel_launch(void* const* d_in, const int* in_sizes, int n_in,
                              void* d_out, int out_size, void* d_ws, size_t ws_size,
                              hipStream_t stream) {
    const float* obs = (const float*)d_in[0];
    const int*   action = (const int*)d_in[1];
    const float* Wfp = (const float*)d_in[2];  const float* bfp = (const float*)d_in[3];
    const float* Wip = (const float*)d_in[4];  const float* bip = (const float*)d_in[5];
    const float* Wcp = (const float*)d_in[6];  const float* bcp = (const float*)d_in[7];
    const float* Wop = (const float*)d_in[8];  const float* bop = (const float*)d_in[9];
    const float* W1  = (const float*)d_in[10]; const float* b1v = (const float*)d_in[11];
    const float* W2  = (const float*)d_in[12]; const float* b2v = (const float*)d_in[13];
    const float* A1  = (const float*)d_in[14]; const float* a1v = (const float*)d_in[15];
    const float* A2  = (const float*)d_in[16]; const float* a2v = (const float*)d_in[17];
    const float* A3  = (const float*)d_in[18]; const float* a3v = (const float*)d_in[19];
    const float* C1  = (const float*)d_in[20]; const float* c1v = (const float*)d_in[21];
    const float* C2  = (const float*)d_in[22]; const float* c2v = (const float*)d_in[23];
    const float* C3  = (const float*)d_in[24]; const float* c3v = (const float*)d_in[25];

    unsigned short* hbuf = (unsigned short*)d_ws;
    unsigned int*   cnt  = (unsigned int*)((char*)d_ws + CNT_OFF_BYTES);

    // zero the per-(group,step) barrier counters (ws is 0xAA-poisoned)
    hipMemsetAsync((char*)d_ws + CNT_OFF_BYTES, 0,
                   MBT * S_LEN * sizeof(unsigned int), stream);

    lstm_recurrence<<<dim3(256), dim3(256), 0, stream>>>(
        obs, Wfp, bfp, Wip, bip, Wcp, bcp, Wop, bop, hbuf, cnt);

    // h_{511} sits in hbuf[0] (written at t=511 to buffer (511+1)&1 = 0)
    head_kernel<<<dim3(64), dim3(256), 0, stream>>>(
        hbuf, W1, b1v, W2, b2v, A1, a1v, A2, a2v, A3, a3v,
        C1, c1v, C2, c2v, C3, c3v, action, (float*)d_out);
}